// Round 1
// baseline (766.646 us; speedup 1.0000x reference)
//
#include <hip/hip_runtime.h>
#include <cstddef>

#define C_DIM  256
#define KD     32
#define NBATCH 4
#define NPIX   4096
#define TR     32
#define TM     128
#define SSHIFT 20.0f

// ws layout (floats)
#define WS_F  0
#define WS_G  (NBATCH*KD*NPIX)          // f,g in [B][K][N]
#define WS_HT (2*NBATCH*KD*NPIX)        // h transposed [B][N][K]
#define WS_OP (3*NBATCH*KD*NPIX)        // o_pre transposed [B][N][K]
#define WS_WT (4*NBATCH*KD*NPIX)        // Wt[C][3*K] transposed f/g/h weights

// ---------------- weight transpose: Wt[c][g*32+k] = W_g[k][c] ----------------
__global__ __launch_bounds__(256) void wt_kernel(const float* __restrict__ Wf,
                                                 const float* __restrict__ Wg,
                                                 const float* __restrict__ Wh,
                                                 float* __restrict__ Wt)
{
    int t = blockIdx.x * 256 + threadIdx.x;          // 0 .. 3*KD*C_DIM
    if (t >= 3 * KD * C_DIM) return;
    int g   = t / (KD * C_DIM);
    int rem = t - g * (KD * C_DIM);
    int k   = rem / C_DIM;
    int c   = rem - k * C_DIM;
    const float* W = (g == 0) ? Wf : ((g == 1) ? Wg : Wh);
    Wt[c * (3 * KD) + g * KD + k] = W[k * C_DIM + c];
}

// ---------------- projections: f,g -> [B][K][N], h -> [B][N][K] ----------------
// block: 256 thr = (n 64) x (k-chunk 4 of 8), grid (N/64, B)
__global__ __launch_bounds__(256) void proj_kernel(const float* __restrict__ x,
                                                   const float* __restrict__ Wt,
                                                   const float* __restrict__ bf,
                                                   const float* __restrict__ bg,
                                                   const float* __restrict__ bh,
                                                   float* __restrict__ fP,
                                                   float* __restrict__ gP,
                                                   float* __restrict__ hT)
{
    const int b  = blockIdx.y;
    const int n  = blockIdx.x * 64 + (int)(threadIdx.x & 63);
    const int kc = (int)(threadIdx.x >> 6);          // 0..3
    const int k0 = kc * 8;

    float af[8], ag[8], ah[8];
#pragma unroll
    for (int j = 0; j < 8; ++j) { af[j] = 0.f; ag[j] = 0.f; ah[j] = 0.f; }

    const float* xp = x + (size_t)b * C_DIM * NPIX + n;
    for (int c = 0; c < C_DIM; ++c) {
        const float xc = xp[(size_t)c * NPIX];                 // coalesced across lanes
        const float* w = Wt + (size_t)c * (3 * KD) + k0;       // wave-uniform -> broadcast
#pragma unroll
        for (int j = 0; j < 8; ++j) {
            af[j] = fmaf(w[j], xc, af[j]);
            ag[j] = fmaf(w[KD + j], xc, ag[j]);
            ah[j] = fmaf(w[2 * KD + j], xc, ah[j]);
        }
    }

#pragma unroll
    for (int j = 0; j < 8; ++j) {
        const int k = k0 + j;
        fP[((size_t)(b * KD + k)) * NPIX + n] = af[j] + bf[k];
        gP[((size_t)(b * KD + k)) * NPIX + n] = ag[j] + bg[k];
    }
    // hT: two float4 stores (32B aligned)
    float4 h0, h1;
    h0.x = ah[0] + bh[k0 + 0]; h0.y = ah[1] + bh[k0 + 1];
    h0.z = ah[2] + bh[k0 + 2]; h0.w = ah[3] + bh[k0 + 3];
    h1.x = ah[4] + bh[k0 + 4]; h1.y = ah[5] + bh[k0 + 5];
    h1.z = ah[6] + bh[k0 + 6]; h1.w = ah[7] + bh[k0 + 7];
    float* hp = hT + ((size_t)(b * NPIX + n)) * KD + k0;
    *(float4*)(hp)     = h0;
    *(float4*)(hp + 4) = h1;
}

// ---------------- fused attention ----------------
// block: 256 thr, TR=32 rows, m tiled by TM=128. grid (N/TR, B).
__global__ __launch_bounds__(256) void attn_kernel(const float* __restrict__ fP,
                                                   const float* __restrict__ gP,
                                                   const float* __restrict__ hT,
                                                   float* __restrict__ am,
                                                   float* __restrict__ oT)
{
    const int b   = blockIdx.y;
    const int r0  = blockIdx.x * TR;
    const int tid = (int)threadIdx.x;

    __shared__ float f_l[KD][TR];     // 4 KB
    __shared__ float g_l[KD][TM];     // 16 KB
    __shared__ float h_l[TM][KD];     // 16 KB
    __shared__ float e_l[TR][TM];     // 16 KB (also reduction scratch)
    __shared__ float rcp_l[TR];

    // stage f block [K][TR]
    {
        const int k  = tid >> 3;
        const int ro = (tid & 7) << 2;
        *(float4*)&f_l[k][ro] =
            *(const float4*)&fP[((size_t)(b * KD + k)) * NPIX + r0 + ro];
    }

    const int mp = tid & 31;   // m-patch (phase A) / k lane (phase B)
    const int rp = tid >> 5;   // r-patch 0..7

    auto stage_g = [&](int m0) {
        const int k  = tid >> 3;
        const int mo = (tid & 7) << 4;
        const float4* src = (const float4*)&gP[((size_t)(b * KD + k)) * NPIX + m0 + mo];
        float4* dst = (float4*)&g_l[k][mo];
        dst[0] = src[0]; dst[1] = src[1]; dst[2] = src[2]; dst[3] = src[3];
    };

    auto compute_s = [&](float acc[4][4]) {
#pragma unroll
        for (int ri = 0; ri < 4; ++ri)
#pragma unroll
            for (int mi = 0; mi < 4; ++mi) acc[ri][mi] = 0.f;
#pragma unroll 8
        for (int k = 0; k < KD; ++k) {
            const float4 fv = *(const float4*)&f_l[k][rp << 2];
            const float4 gv = *(const float4*)&g_l[k][mp << 2];
            acc[0][0] = fmaf(fv.x, gv.x, acc[0][0]); acc[0][1] = fmaf(fv.x, gv.y, acc[0][1]);
            acc[0][2] = fmaf(fv.x, gv.z, acc[0][2]); acc[0][3] = fmaf(fv.x, gv.w, acc[0][3]);
            acc[1][0] = fmaf(fv.y, gv.x, acc[1][0]); acc[1][1] = fmaf(fv.y, gv.y, acc[1][1]);
            acc[1][2] = fmaf(fv.y, gv.z, acc[1][2]); acc[1][3] = fmaf(fv.y, gv.w, acc[1][3]);
            acc[2][0] = fmaf(fv.z, gv.x, acc[2][0]); acc[2][1] = fmaf(fv.z, gv.y, acc[2][1]);
            acc[2][2] = fmaf(fv.z, gv.z, acc[2][2]); acc[2][3] = fmaf(fv.z, gv.w, acc[2][3]);
            acc[3][0] = fmaf(fv.w, gv.x, acc[3][0]); acc[3][1] = fmaf(fv.w, gv.y, acc[3][1]);
            acc[3][2] = fmaf(fv.w, gv.z, acc[3][2]); acc[3][3] = fmaf(fv.w, gv.w, acc[3][3]);
        }
    };

    float sum_part[4] = {0.f, 0.f, 0.f, 0.f};
    float o_acc[4]    = {0.f, 0.f, 0.f, 0.f};

    // ---------------- pass 1: sumexp + unnormalized o_pre ----------------
    for (int m0 = 0; m0 < NPIX; m0 += TM) {
        stage_g(m0);
        {   // stage h tile [TM][KD] (same flat layout as hT rows)
            const float4* src = (const float4*)&hT[((size_t)(b * NPIX + m0)) * KD + tid * 16];
            float4* dst = (float4*)((float*)h_l + tid * 16);
            dst[0] = src[0]; dst[1] = src[1]; dst[2] = src[2]; dst[3] = src[3];
        }
        __syncthreads();

        float acc[4][4];
        compute_s(acc);
#pragma unroll
        for (int ri = 0; ri < 4; ++ri) {
            float4 ev;
            ev.x = __expf(acc[ri][0] - SSHIFT);
            ev.y = __expf(acc[ri][1] - SSHIFT);
            ev.z = __expf(acc[ri][2] - SSHIFT);
            ev.w = __expf(acc[ri][3] - SSHIFT);
            sum_part[ri] += (ev.x + ev.y) + (ev.z + ev.w);
            *(float4*)&e_l[(rp << 2) + ri][mp << 2] = ev;
        }
        __syncthreads();

        // phase B: o_acc[j] for r = rp*4+j, k lane = mp
#pragma unroll 8
        for (int mc = 0; mc < TM; mc += 4) {
            const float h0 = h_l[mc + 0][mp];
            const float h1 = h_l[mc + 1][mp];
            const float h2 = h_l[mc + 2][mp];
            const float h3 = h_l[mc + 3][mp];
#pragma unroll
            for (int j = 0; j < 4; ++j) {
                const float4 ev = *(const float4*)&e_l[(rp << 2) + j][mc];
                o_acc[j] += ev.x * h0 + ev.y * h1 + ev.z * h2 + ev.w * h3;
            }
        }
        __syncthreads();
    }

    // reduce sumexp across the 32 m-lanes (scratch in e_l)
#pragma unroll
    for (int ri = 0; ri < 4; ++ri)
        ((float*)e_l)[((rp << 2) + ri) * 32 + mp] = sum_part[ri];
    __syncthreads();
    if (tid < TR) {
        float s = 0.f;
        const float* row = (const float*)e_l + tid * 32;
#pragma unroll
        for (int i = 0; i < 32; ++i) s += row[i];
        rcp_l[tid] = 1.0f / s;
    }
    __syncthreads();

    // store normalized o_pre: oT[b][r][k]
#pragma unroll
    for (int j = 0; j < 4; ++j) {
        const int r = (rp << 2) + j;
        oT[((size_t)(b * NPIX + r0 + r)) * KD + mp] = o_acc[j] * rcp_l[r];
    }

    // ---------------- pass 2: recompute s, write attn_map transposed ----------------
    for (int m0 = 0; m0 < NPIX; m0 += TM) {
        stage_g(m0);
        __syncthreads();

        float acc[4][4];
        compute_s(acc);
#pragma unroll
        for (int ri = 0; ri < 4; ++ri) {
            const int r   = (rp << 2) + ri;
            const float rc = rcp_l[r];
            float4 av;
            av.x = __expf(acc[ri][0] - SSHIFT) * rc;
            av.y = __expf(acc[ri][1] - SSHIFT) * rc;
            av.z = __expf(acc[ri][2] - SSHIFT) * rc;
            av.w = __expf(acc[ri][3] - SSHIFT) * rc;
            *(float4*)&e_l[r][mp << 2] = av;
        }
        __syncthreads();

        // cooperative store: 2 threads per m-row, each writes 16 consecutive r
        {
            const int m    = tid >> 1;
            const int half = tid & 1;
            float* dst = am + (size_t)b * NPIX * NPIX + (size_t)(m0 + m) * NPIX
                         + r0 + half * 16;
#pragma unroll
            for (int q = 0; q < 4; ++q) {
                float4 v;
                v.x = e_l[half * 16 + q * 4 + 0][m];
                v.y = e_l[half * 16 + q * 4 + 1][m];
                v.z = e_l[half * 16 + q * 4 + 2][m];
                v.w = e_l[half * 16 + q * 4 + 3][m];
                *(float4*)(dst + q * 4) = v;
            }
        }
    }
}

// ---------------- output: y = gamma*(Wv@o_pre + bv) + x ----------------
// block: 256 thr = (n 64) x (c-group 4 of 64), grid (N/64, B)
__global__ __launch_bounds__(256) void out_kernel(const float* __restrict__ x,
                                                  const float* __restrict__ oT,
                                                  const float* __restrict__ Wv,
                                                  const float* __restrict__ bv,
                                                  const float* __restrict__ gamma,
                                                  float* __restrict__ y)
{
    const int b  = blockIdx.y;
    const int n  = blockIdx.x * 64 + (int)(threadIdx.x & 63);
    const int cg = (int)(threadIdx.x >> 6);
    const float gm = gamma[0];

    float op[KD];
    {
        const float4* src = (const float4*)&oT[((size_t)(b * NPIX + n)) * KD];
#pragma unroll
        for (int q = 0; q < 8; ++q) {
            const float4 v = src[q];
            op[q * 4 + 0] = v.x; op[q * 4 + 1] = v.y;
            op[q * 4 + 2] = v.z; op[q * 4 + 3] = v.w;
        }
    }

    for (int c = cg * 64; c < cg * 64 + 64; ++c) {
        const float* w = &Wv[c * KD];        // wave-uniform -> broadcast
        float acc = 0.f;
#pragma unroll
        for (int k = 0; k < KD; ++k) acc = fmaf(w[k], op[k], acc);
        const size_t idx = ((size_t)(b * C_DIM + c)) * NPIX + n;
        y[idx] = fmaf(gm, acc + bv[c], x[idx]);
    }
}

extern "C" void kernel_launch(void* const* d_in, const int* in_sizes, int n_in,
                              void* d_out, int out_size, void* d_ws, size_t ws_size,
                              hipStream_t stream)
{
    const float* x     = (const float*)d_in[0];
    const float* Wf    = (const float*)d_in[1];
    const float* bf    = (const float*)d_in[2];
    const float* Wg    = (const float*)d_in[3];
    const float* bg    = (const float*)d_in[4];
    const float* Wh    = (const float*)d_in[5];
    const float* bh    = (const float*)d_in[6];
    const float* Wv    = (const float*)d_in[7];
    const float* bv    = (const float*)d_in[8];
    const float* gamma = (const float*)d_in[9];

    float* ws = (float*)d_ws;
    float* fP = ws + WS_F;
    float* gP = ws + WS_G;
    float* hT = ws + WS_HT;
    float* oT = ws + WS_OP;
    float* Wt = ws + WS_WT;

    float* y  = (float*)d_out;
    float* am = (float*)d_out + (size_t)NBATCH * C_DIM * NPIX;   // attn_map [B][N][N]

    hipLaunchKernelGGL(wt_kernel,  dim3(96), dim3(256), 0, stream, Wf, Wg, Wh, Wt);
    hipLaunchKernelGGL(proj_kernel, dim3(NPIX / 64, NBATCH), dim3(256), 0, stream,
                       x, Wt, bf, bg, bh, fP, gP, hT);
    hipLaunchKernelGGL(attn_kernel, dim3(NPIX / TR, NBATCH), dim3(256), 0, stream,
                       fP, gP, hT, am, oT);
    hipLaunchKernelGGL(out_kernel, dim3(NPIX / 64, NBATCH), dim3(256), 0, stream,
                       x, oT, Wv, bv, gamma, y);
}

// Round 2
// 437.805 us; speedup vs baseline: 1.7511x; 1.7511x over previous
//
#include <hip/hip_runtime.h>
#include <cstddef>
#include <cstdint>

#define NB     4
#define CDIM   256
#define KD     32
#define NPIX   4096
#define SSHIFT 20.0f

typedef __attribute__((ext_vector_type(8))) short  bfrag;   // 8 bf16
typedef __attribute__((ext_vector_type(4))) float  facc;    // 4 fp32

#define MFMA(a,b,c) __builtin_amdgcn_mfma_f32_16x16x32_bf16((a),(b),(c),0,0,0)

__device__ __forceinline__ unsigned short f2bf(float x) {
    union { float f; unsigned u; } v; v.f = x;
    unsigned u = v.u + 0x7fffu + ((v.u >> 16) & 1u);
    return (unsigned short)(u >> 16);
}
__device__ __forceinline__ float bf2f(unsigned short h) {
    union { float f; unsigned u; } v; v.u = ((unsigned)h) << 16;
    return v.f;
}

// ws byte offsets -------------------------------------------------------------
// fA_hi/fA_lo : [B][256 rt][64 lane][8] bf16   (A-frag of f^T, K=32)      1 MB ea
// gB_hi/gB_lo : [B][256 mt][64 lane][8] bf16   (B-frag of g)              1 MB ea
// hB          : [B][128 mc][2 kt][64 lane][8]  (B-frag of h, perm order)  1 MB
// WA_hi/WA_lo : [6 rt][8 cc][64 lane][8] bf16  (A-frag of [Wf;Wg;Wh])     48 KB ea
// oT          : [B][4096 n][32 k] f32 (normalized o_pre^T)                2 MB
#define OFF_FA_HI (0)
#define OFF_FA_LO (1u<<20)
#define OFF_GB_HI (2u<<20)
#define OFF_GB_LO (3u<<20)
#define OFF_HB    (4u<<20)
#define OFF_WA_HI (5u<<20)
#define OFF_WA_LO ((5u<<20) + 65536)
#define OFF_OT    ((5u<<20) + 131072)

// ---------------- wt: W' = [Wf;Wg;Wh] -> A-fragments hi/lo -------------------
__global__ __launch_bounds__(256) void wt_kernel(const float* __restrict__ Wf,
                                                 const float* __restrict__ Wg,
                                                 const float* __restrict__ Wh,
                                                 unsigned short* __restrict__ WA_hi,
                                                 unsigned short* __restrict__ WA_lo)
{
    int t = blockIdx.x * 256 + threadIdx.x;      // 48 tiles * 64 lanes
    if (t >= 48 * 64) return;
    int tile = t >> 6, lane = t & 63;
    int rt = tile >> 3, cc = tile & 7;
    int q = lane >> 4, c15 = lane & 15;
    int row = rt * 16 + c15;
    const float* W = (row < 32) ? (Wf + (size_t)row * CDIM)
                   : (row < 64) ? (Wg + (size_t)(row - 32) * CDIM)
                                : (Wh + (size_t)(row - 64) * CDIM);
    int cb = cc * 32 + q * 8;
    bfrag vh, vl;
#pragma unroll
    for (int j = 0; j < 8; ++j) {
        float xv = W[cb + j];
        unsigned short h = f2bf(xv);
        vh[j] = (short)h;
        vl[j] = (short)f2bf(xv - bf2f(h));
    }
    *(bfrag*)(WA_hi + (size_t)t * 8) = vh;
    *(bfrag*)(WA_lo + (size_t)t * 8) = vl;
}

// ---------------- proj: MFMA GEMM [96 x 256] x [256 x n] -> fragments --------
__global__ __launch_bounds__(256) void proj_kernel(const float* __restrict__ x,
                                                   const unsigned short* __restrict__ WA_hi,
                                                   const unsigned short* __restrict__ WA_lo,
                                                   const float* __restrict__ bfv,
                                                   const float* __restrict__ bgv,
                                                   const float* __restrict__ bhv,
                                                   unsigned short* __restrict__ fA_hi,
                                                   unsigned short* __restrict__ fA_lo,
                                                   unsigned short* __restrict__ gB_hi,
                                                   unsigned short* __restrict__ gB_lo,
                                                   unsigned short* __restrict__ hB)
{
    __shared__ float xs[32][65];
    __shared__ float os[96][65];
    __shared__ float bias_s[96];

    const int b  = blockIdx.y;
    const int n0 = blockIdx.x * 64;
    const int tid = threadIdx.x;
    const int w = tid >> 6, lane = tid & 63, q = lane >> 4, c15 = lane & 15;

    if (tid < 96)
        bias_s[tid] = (tid < 32) ? bfv[tid] : (tid < 64 ? bgv[tid - 32] : bhv[tid - 64]);

    facc acc[6];
#pragma unroll
    for (int rt = 0; rt < 6; ++rt) acc[rt] = (facc){0.f, 0.f, 0.f, 0.f};

    const float* xb = x + (size_t)b * CDIM * NPIX + n0;
    const int cr = tid >> 3, nb = (tid & 7) * 8;

    for (int cc = 0; cc < 8; ++cc) {
        const float* src = xb + (size_t)(cc * 32 + cr) * NPIX + nb;
        float4 va = *(const float4*)src;
        float4 vb = *(const float4*)(src + 4);
        __syncthreads();
        *(float4*)&xs[cr][nb]     = va;
        *(float4*)&xs[cr][nb + 4] = vb;
        __syncthreads();

        bfrag xh, xl;
#pragma unroll
        for (int j = 0; j < 8; ++j) {
            float xv = xs[q * 8 + j][w * 16 + c15];
            unsigned short h = f2bf(xv);
            xh[j] = (short)h;
            xl[j] = (short)f2bf(xv - bf2f(h));
        }
#pragma unroll
        for (int rt = 0; rt < 6; ++rt) {
            size_t wo = ((size_t)(rt * 8 + cc) * 64 + lane) * 8;
            bfrag wh = *(const bfrag*)(WA_hi + wo);
            bfrag wl = *(const bfrag*)(WA_lo + wo);
            acc[rt] = MFMA(wh, xh, acc[rt]);
            acc[rt] = MFMA(wh, xl, acc[rt]);
            acc[rt] = MFMA(wl, xh, acc[rt]);
        }
    }

    // C-frag (col=lane&15, row=quad*4+i) -> os[row][n_local], add bias
#pragma unroll
    for (int rt = 0; rt < 6; ++rt)
#pragma unroll
        for (int i = 0; i < 4; ++i) {
            int row = rt * 16 + q * 4 + i;
            os[row][w * 16 + c15] = acc[rt][i] + bias_s[row];
        }
    __syncthreads();

    // fragment outputs: wave w handles n-tile w / h-unit w
    {
        bfrag vh, vl;
        // fA (rows 0..31): element j -> k = q*8+j, row (of A) = n
#pragma unroll
        for (int j = 0; j < 8; ++j) {
            float v = os[q * 8 + j][w * 16 + c15];
            unsigned short h = f2bf(v);
            vh[j] = (short)h; vl[j] = (short)f2bf(v - bf2f(h));
        }
        size_t o = ((size_t)(b * 256 + (n0 >> 4) + w) * 64 + lane) * 8;
        *(bfrag*)(fA_hi + o) = vh;
        *(bfrag*)(fA_lo + o) = vl;
        // gB (rows 32..63): element j -> k = q*8+j, col = n
#pragma unroll
        for (int j = 0; j < 8; ++j) {
            float v = os[32 + q * 8 + j][w * 16 + c15];
            unsigned short h = f2bf(v);
            vh[j] = (short)h; vl[j] = (short)f2bf(v - bf2f(h));
        }
        *(bfrag*)(gB_hi + o) = vh;
        *(bfrag*)(gB_lo + o) = vl;
        // hB (rows 64..95): B[m][k], contraction m in permuted physical order
        int mcl = w >> 1, kt = w & 1;
        bfrag hv;
#pragma unroll
        for (int j = 0; j < 8; ++j) {
            int p = q * 8 + j;
            int mp = (p & 1) * 16 + (p >> 1);          // perm: phys -> logical m
            float v = os[64 + kt * 16 + c15][mcl * 32 + mp];
            hv[j] = (short)f2bf(v);
        }
        size_t oh = ((size_t)((b * 128 + (n0 >> 5) + mcl) * 2 + kt) * 64 + lane) * 8;
        *(bfrag*)(hB + oh) = hv;
    }
}

// ---------------- attention: MFMA flash-style, 16 rows/block, 4-way m-split --
__global__ __launch_bounds__(256) void attn_kernel(const unsigned short* __restrict__ fA_hi,
                                                   const unsigned short* __restrict__ fA_lo,
                                                   const unsigned short* __restrict__ gB_hi,
                                                   const unsigned short* __restrict__ gB_lo,
                                                   const unsigned short* __restrict__ hB,
                                                   float* __restrict__ am,
                                                   float* __restrict__ oT)
{
    __shared__ unsigned short Pst[4][16 * 40];  // per-wave P tile, row stride 40 bf16
    __shared__ float red[4][64][8];             // cross-wave o_pre reduce
    __shared__ float sums_l[4][16];
    __shared__ float rcp_l[16];
    __shared__ float st2[4][16 * 33];           // pass2 [r][m] staging, stride 33

    const int b  = blockIdx.y;
    const int r0 = blockIdx.x * 16;
    const int tid = threadIdx.x;
    const int w = tid >> 6, lane = tid & 63, q = lane >> 4, c15 = lane & 15;

    const size_t fo = ((size_t)(b * 256 + (r0 >> 4)) * 64 + lane) * 8;
    const bfrag fh = *(const bfrag*)(fA_hi + fo);
    const bfrag fl = *(const bfrag*)(fA_lo + fo);

    facc o0 = (facc){0.f,0.f,0.f,0.f}, o1 = (facc){0.f,0.f,0.f,0.f};
    float sum[4] = {0.f, 0.f, 0.f, 0.f};
    unsigned short* P = &Pst[w][0];

    const int ch0 = w * 32, ch1 = ch0 + 32;

    // ---- pass 1: rowsums + unnormalized o_pre ----
    for (int mc = ch0; mc < ch1; ++mc) {
        size_t go = ((size_t)(b * 256 + 2 * mc) * 64 + lane) * 8;
        bfrag g0h = *(const bfrag*)(gB_hi + go);
        bfrag g1h = *(const bfrag*)(gB_hi + go + 512);
        bfrag g0l = *(const bfrag*)(gB_lo + go);
        bfrag g1l = *(const bfrag*)(gB_lo + go + 512);
        size_t ho = ((size_t)(b * 128 + mc) * 2 * 64 + lane) * 8;
        bfrag h0 = *(const bfrag*)(hB + ho);
        bfrag h1 = *(const bfrag*)(hB + ho + 512);

        facc s0 = (facc){0.f,0.f,0.f,0.f}, s1 = (facc){0.f,0.f,0.f,0.f};
        s0 = MFMA(fh, g0h, s0); s0 = MFMA(fh, g0l, s0); s0 = MFMA(fl, g0h, s0);
        s1 = MFMA(fh, g1h, s1); s1 = MFMA(fh, g1l, s1); s1 = MFMA(fl, g1h, s1);

        float e0[4], e1[4];
#pragma unroll
        for (int i = 0; i < 4; ++i) {
            e0[i] = __expf(s0[i] - SSHIFT);
            e1[i] = __expf(s1[i] - SSHIFT);
            sum[i] += e0[i] + e1[i];
        }
        // stage P in A-frag-compatible physical order: pair (m, m+16) adjacent
#pragma unroll
        for (int i = 0; i < 4; ++i) {
            unsigned pr = (unsigned)f2bf(e0[i]) | ((unsigned)f2bf(e1[i]) << 16);
            *(unsigned*)&P[(4 * q + i) * 40 + 2 * c15] = pr;
        }
        bfrag pA = *(const bfrag*)&P[c15 * 40 + q * 8];
        o0 = MFMA(pA, h0, o0);
        o1 = MFMA(pA, h1, o1);
    }

    // reduce rowsums over the 16 col-lanes of each quad
#pragma unroll
    for (int m = 1; m < 16; m <<= 1)
#pragma unroll
        for (int i = 0; i < 4; ++i) sum[i] += __shfl_xor(sum[i], m);
    if (c15 == 0) {
#pragma unroll
        for (int i = 0; i < 4; ++i) sums_l[w][4 * q + i] = sum[i];
    }
    *(facc*)&red[w][lane][0] = o0;
    *(facc*)&red[w][lane][4] = o1;
    __syncthreads();
    if (tid < 16)
        rcp_l[tid] = 1.0f / (sums_l[0][tid] + sums_l[1][tid] + sums_l[2][tid] + sums_l[3][tid]);
    __syncthreads();

    float rcpv[4];
#pragma unroll
    for (int i = 0; i < 4; ++i) rcpv[i] = rcp_l[4 * q + i];

    if (w == 0) {   // reduce o_pre across waves, normalize, store oT
        facc a = (facc){0.f,0.f,0.f,0.f}, bb = (facc){0.f,0.f,0.f,0.f};
#pragma unroll
        for (int ww = 0; ww < 4; ++ww) {
            a  += *(const facc*)&red[ww][lane][0];
            bb += *(const facc*)&red[ww][lane][4];
        }
#pragma unroll
        for (int i = 0; i < 4; ++i) {
            int r = 4 * q + i;
            float rc = rcp_l[r];
            oT[((size_t)(b * NPIX + r0 + r)) * KD + c15]      = a[i] * rc;
            oT[((size_t)(b * NPIX + r0 + r)) * KD + 16 + c15] = bb[i] * rc;
        }
    }

    // ---- pass 2: recompute s, write normalized attn transposed ----
    float* S2 = &st2[w][0];
    const int mr = lane >> 2, ro = (lane & 3) * 4;
    for (int mc = ch0; mc < ch1; ++mc) {
        size_t go = ((size_t)(b * 256 + 2 * mc) * 64 + lane) * 8;
        bfrag g0h = *(const bfrag*)(gB_hi + go);
        bfrag g1h = *(const bfrag*)(gB_hi + go + 512);
        bfrag g0l = *(const bfrag*)(gB_lo + go);
        bfrag g1l = *(const bfrag*)(gB_lo + go + 512);

        facc s0 = (facc){0.f,0.f,0.f,0.f}, s1 = (facc){0.f,0.f,0.f,0.f};
        s0 = MFMA(fh, g0h, s0); s0 = MFMA(fh, g0l, s0); s0 = MFMA(fl, g0h, s0);
        s1 = MFMA(fh, g1h, s1); s1 = MFMA(fh, g1l, s1); s1 = MFMA(fl, g1h, s1);

#pragma unroll
        for (int i = 0; i < 4; ++i) {
            S2[(4 * q + i) * 33 + c15]      = __expf(s0[i] - SSHIFT) * rcpv[i];
            S2[(4 * q + i) * 33 + 16 + c15] = __expf(s1[i] - SSHIFT) * rcpv[i];
        }
        // per-wave transpose read (in-order DS pipe: no barrier needed)
        float4 v0, v1;
        v0.x = S2[(ro + 0) * 33 + mr];      v0.y = S2[(ro + 1) * 33 + mr];
        v0.z = S2[(ro + 2) * 33 + mr];      v0.w = S2[(ro + 3) * 33 + mr];
        v1.x = S2[(ro + 0) * 33 + 16 + mr]; v1.y = S2[(ro + 1) * 33 + 16 + mr];
        v1.z = S2[(ro + 2) * 33 + 16 + mr]; v1.w = S2[(ro + 3) * 33 + 16 + mr];
        size_t ao = (size_t)b * NPIX * NPIX + (size_t)(mc * 32 + mr) * NPIX + r0 + ro;
        *(float4*)(am + ao)             = v0;
        *(float4*)(am + ao + 16 * NPIX) = v1;
    }
}

// ---------------- out: y = gamma*(Wv@o_pre + bv) + x -------------------------
__global__ __launch_bounds__(256) void out_kernel(const float* __restrict__ x,
                                                  const float* __restrict__ oT,
                                                  const float* __restrict__ Wv,
                                                  const float* __restrict__ bv,
                                                  const float* __restrict__ gamma,
                                                  float* __restrict__ y)
{
    __shared__ float wv_s[CDIM * KD];   // 32 KB
    const int b  = blockIdx.y;
    const int tid = threadIdx.x;
    const int n = blockIdx.x * 64 + (tid & 63);
    const int cg = tid >> 6;

    for (int i = tid * 4; i < CDIM * KD; i += 1024)
        *(float4*)&wv_s[i] = *(const float4*)&Wv[i];

    float op[KD];
    {
        const float4* src = (const float4*)&oT[((size_t)(b * NPIX + n)) * KD];
#pragma unroll
        for (int qq = 0; qq < 8; ++qq) {
            float4 v = src[qq];
            op[qq * 4 + 0] = v.x; op[qq * 4 + 1] = v.y;
            op[qq * 4 + 2] = v.z; op[qq * 4 + 3] = v.w;
        }
    }
    __syncthreads();
    const float gm = gamma[0];

    for (int c = cg * 64; c < cg * 64 + 64; ++c) {
        float a = 0.f;
#pragma unroll
        for (int k4 = 0; k4 < 8; ++k4) {
            float4 wv4 = *(const float4*)&wv_s[c * KD + k4 * 4];
            a = fmaf(wv4.x, op[k4 * 4 + 0], a);
            a = fmaf(wv4.y, op[k4 * 4 + 1], a);
            a = fmaf(wv4.z, op[k4 * 4 + 2], a);
            a = fmaf(wv4.w, op[k4 * 4 + 3], a);
        }
        size_t idx = ((size_t)(b * CDIM + c)) * NPIX + n;
        y[idx] = fmaf(gm, a + bv[c], x[idx]);
    }
}

extern "C" void kernel_launch(void* const* d_in, const int* in_sizes, int n_in,
                              void* d_out, int out_size, void* d_ws, size_t ws_size,
                              hipStream_t stream)
{
    const float* x     = (const float*)d_in[0];
    const float* Wf    = (const float*)d_in[1];
    const float* bfv   = (const float*)d_in[2];
    const float* Wg    = (const float*)d_in[3];
    const float* bgv   = (const float*)d_in[4];
    const float* Wh    = (const float*)d_in[5];
    const float* bhv   = (const float*)d_in[6];
    const float* Wv    = (const float*)d_in[7];
    const float* bv    = (const float*)d_in[8];
    const float* gamma = (const float*)d_in[9];

    char* ws = (char*)d_ws;
    unsigned short* fA_hi = (unsigned short*)(ws + OFF_FA_HI);
    unsigned short* fA_lo = (unsigned short*)(ws + OFF_FA_LO);
    unsigned short* gB_hi = (unsigned short*)(ws + OFF_GB_HI);
    unsigned short* gB_lo = (unsigned short*)(ws + OFF_GB_LO);
    unsigned short* hB    = (unsigned short*)(ws + OFF_HB);
    unsigned short* WA_hi = (unsigned short*)(ws + OFF_WA_HI);
    unsigned short* WA_lo = (unsigned short*)(ws + OFF_WA_LO);
    float*          oT    = (float*)(ws + OFF_OT);

    float* y  = (float*)d_out;
    float* am = (float*)d_out + (size_t)NB * CDIM * NPIX;

    hipLaunchKernelGGL(wt_kernel, dim3(12), dim3(256), 0, stream, Wf, Wg, Wh, WA_hi, WA_lo);
    hipLaunchKernelGGL(proj_kernel, dim3(NPIX / 64, NB), dim3(256), 0, stream,
                       x, WA_hi, WA_lo, bfv, bgv, bhv, fA_hi, fA_lo, gB_hi, gB_lo, hB);
    hipLaunchKernelGGL(attn_kernel, dim3(NPIX / 16, NB), dim3(256), 0, stream,
                       fA_hi, fA_lo, gB_hi, gB_lo, hB, am, oT);
    hipLaunchKernelGGL(out_kernel, dim3(NPIX / 64, NB), dim3(256), 0, stream,
                       x, oT, Wv, bv, gamma, y);
}